// Round 12
// baseline (67.013 us; speedup 1.0000x reference)
//
#include <hip/hip_runtime.h>
#include <hip/hip_bf16.h>

#define DIM 768
#define LTOK 1024
#define NBATCH 32
#define KEEP 256

// Correctly-rounded f32 reciprocal robust to compile flags (matches np's
// hoisted `inv = 1/den` reciprocal-multiply chain, proven in R9).
__device__ __forceinline__ float recip_cr_f32(float b) {
    return (float)(1.0 / (double)b);
}

// term[c] = (c/768)*log(c/768 + 1e-9) in f64 — same expression as R9's
// in-kernel TERM, so downstream entropies stay bit-identical.
__global__ __launch_bounds__(256) void table_kernel(double* __restrict__ term) {
    int i = blockIdx.x * 256 + threadIdx.x;
    if (i <= DIM) {
        double p = (double)i / 768.0;
        term[i] = p * log(p + 1e-9);
    }
}

// TWO rows per wave (lanes 0-31 / 32-63), 24 elems per lane.
// R9-verified np binning chain (DO NOT TOUCH):
//   den = (mx-mn)+1e-19f ; inv = RN32(1/den) ; nrm = RN32(s*inv) ;
//   t = RN32(nrm*9) ; q = (int)t  [trunc==floor, q in 0..9 provable].
// Ends at the packed count vector — NO f64, NO table, no long-latency tail:
// writes {lo,hi} (10x12-bit counts) per row.  Entropy moved to rank_kernel.
__global__ __launch_bounds__(256) void ent_kernel(const float* __restrict__ x,
                                                  ulonglong2* __restrict__ cnt) {
    int wave = blockIdx.x * 4 + (threadIdx.x >> 6);   // 0..16383
    int wid  = wave * 2;                              // first of 2 rows
    int lane = threadIdx.x & 63;
    int g    = lane >> 5;                             // 0: row wid, 1: wid+1
    int il   = lane & 31;
    const float* row = x + (size_t)(wid + g) * DIM;

    float4 v0 = *(const float4*)(row + il * 4);
    float4 v1 = *(const float4*)(row + il * 4 + 128);
    float4 v2 = *(const float4*)(row + il * 4 + 256);
    float4 v3 = *(const float4*)(row + il * 4 + 384);
    float4 v4 = *(const float4*)(row + il * 4 + 512);
    float4 v5 = *(const float4*)(row + il * 4 + 640);

    float mn = v0.x;
    mn = fminf(mn, v0.y); mn = fminf(mn, v0.z); mn = fminf(mn, v0.w);
    mn = fminf(mn, v1.x); mn = fminf(mn, v1.y); mn = fminf(mn, v1.z); mn = fminf(mn, v1.w);
    mn = fminf(mn, v2.x); mn = fminf(mn, v2.y); mn = fminf(mn, v2.z); mn = fminf(mn, v2.w);
    mn = fminf(mn, v3.x); mn = fminf(mn, v3.y); mn = fminf(mn, v3.z); mn = fminf(mn, v3.w);
    mn = fminf(mn, v4.x); mn = fminf(mn, v4.y); mn = fminf(mn, v4.z); mn = fminf(mn, v4.w);
    mn = fminf(mn, v5.x); mn = fminf(mn, v5.y); mn = fminf(mn, v5.z); mn = fminf(mn, v5.w);
    float mx = v0.x;
    mx = fmaxf(mx, v0.y); mx = fmaxf(mx, v0.z); mx = fmaxf(mx, v0.w);
    mx = fmaxf(mx, v1.x); mx = fmaxf(mx, v1.y); mx = fmaxf(mx, v1.z); mx = fmaxf(mx, v1.w);
    mx = fmaxf(mx, v2.x); mx = fmaxf(mx, v2.y); mx = fmaxf(mx, v2.z); mx = fmaxf(mx, v2.w);
    mx = fmaxf(mx, v3.x); mx = fmaxf(mx, v3.y); mx = fmaxf(mx, v3.z); mx = fmaxf(mx, v3.w);
    mx = fmaxf(mx, v4.x); mx = fmaxf(mx, v4.y); mx = fmaxf(mx, v4.z); mx = fmaxf(mx, v4.w);
    mx = fmaxf(mx, v5.x); mx = fmaxf(mx, v5.y); mx = fmaxf(mx, v5.z); mx = fmaxf(mx, v5.w);

    // 32-lane butterfly (xor<32 keeps lanes within their half)
    #pragma unroll
    for (int off = 16; off > 0; off >>= 1) {
        mn = fminf(mn, __shfl_xor(mn, off, 64));
        mx = fmaxf(mx, __shfl_xor(mx, off, 64));
    }

    float den = (mx - mn) + 1e-19f;     // 1e-19 absorbed
    float inv = recip_cr_f32(den);      // RN32(1/den)

    unsigned long long pk = 0ull;       // 10 bins x 6 bits; per-lane max 24
    #define ACC(v) do { float s_  = (v) - mn;                              \
                        float nr_ = s_ * inv;      /* RN32, lone mul */    \
                        float t_  = nr_ * 9.0f;    /* RN32, lone mul */    \
                        unsigned q = (unsigned)t_; /* trunc==floor, 0..9 */\
                        pk = (1ull << (6u * q)) + pk; } while (0)
    ACC(v0.x); ACC(v0.y); ACC(v0.z); ACC(v0.w);
    ACC(v1.x); ACC(v1.y); ACC(v1.z); ACC(v1.w);
    ACC(v2.x); ACC(v2.y); ACC(v2.z); ACC(v2.w);
    ACC(v3.x); ACC(v3.y); ACC(v3.z); ACC(v3.w);
    ACC(v4.x); ACC(v4.y); ACC(v4.z); ACC(v4.w);
    ACC(v5.x); ACC(v5.y); ACC(v5.z); ACC(v5.w);
    #undef ACC

    // one 6-bit-packed level first (sum <= 48 per field, no overflow)
    pk += __shfl_xor(pk, 1, 64);

    // widen: bins 0-4 -> lo (12-bit fields), bins 5-9 -> hi
    unsigned long long lo = 0ull, hi = 0ull;
    #pragma unroll
    for (int i = 0; i < 5; ++i) {
        lo |= ((pk >> (6 * i)) & 63ull) << (12 * i);
        hi |= ((pk >> (6 * (i + 5))) & 63ull) << (12 * i);
    }
    #pragma unroll
    for (int off = 2; off <= 16; off <<= 1) {
        lo += __shfl_xor(lo, off, 64);
        hi += __shfl_xor(hi, off, 64);
    }

    if (il == 0) {
        ulonglong2 c; c.x = lo; c.y = hi;
        cnt[wid + g] = c;
    }
}

// Per (batch, chunk) block: stage term table + compute entropies from packed
// counts (bit-identical formula/order to R11), then the stable rank loop.
// rank(l) = #{j : e_j > e_l} + #{j < l : e_j == e_l}  (== ids_restore)
__global__ __launch_bounds__(128) void rank_kernel(const ulonglong2* __restrict__ cnt,
                                                   const double* __restrict__ term,
                                                   int* __restrict__ keep,
                                                   float* __restrict__ out_mask,
                                                   float* __restrict__ out_restore) {
    __shared__ double se[LTOK];
    __shared__ double sterm[DIM + 1];
    int n = blockIdx.x;      // 0..31
    int chunk = blockIdx.y;  // 0..7

    for (int i = threadIdx.x; i <= DIM; i += 128)
        sterm[i] = term[i];
    __syncthreads();

    for (int r = threadIdx.x; r < LTOK; r += 128) {
        ulonglong2 c = cnt[n * LTOK + r];
        unsigned long long lo = c.x, hi = c.y;
        double t0 = sterm[(lo      ) & 4095ull];
        double t1 = sterm[(lo >> 12) & 4095ull];
        double t2 = sterm[(lo >> 24) & 4095ull];
        double t3 = sterm[(lo >> 36) & 4095ull];
        double t4 = sterm[(lo >> 48) & 4095ull];
        double t5 = sterm[(hi      ) & 4095ull];
        double t6 = sterm[(hi >> 12) & 4095ull];
        double t7 = sterm[(hi >> 24) & 4095ull];
        double t8 = sterm[(hi >> 36) & 4095ull];
        double t9 = sterm[(hi >> 48) & 4095ull];
        // numpy pairwise order for n=10: tree over first 8, then +t8, +t9
        double s = ((t0 + t1) + (t2 + t3)) + ((t4 + t5) + (t6 + t7));
        s += t8;
        s += t9;
        se[r] = -s;
    }
    __syncthreads();

    int l = chunk * 128 + threadIdx.x;
    double e = se[l];
    int rank = 0;
    #pragma unroll 8
    for (int j = 0; j < LTOK; ++j) {
        double ej = se[j];
        rank += (int)((ej > e) | ((ej == e) & (j < l)));
    }
    out_restore[n * LTOK + l] = (float)rank;
    out_mask[n * LTOK + l]    = (rank < KEEP) ? 0.0f : 1.0f;
    if (rank < KEEP) keep[n * KEEP + rank] = l;   // ids_shuffle[rank] = l
}

// One wave per kept row: x_masked[n, r, :] = x[n, keep[n,r], :]  (f32 copy)
__global__ __launch_bounds__(256) void gather_kernel(const float* __restrict__ x,
                                                     const int* __restrict__ keep,
                                                     float* __restrict__ xm) {
    int r    = blockIdx.x * 4 + (threadIdx.x >> 6);  // 0..8191
    int lane = threadIdx.x & 63;
    int n = r >> 8;
    int k = r & 255;
    int src = keep[n * KEEP + k];
    const float* srow = x + ((size_t)n * LTOK + (size_t)src) * DIM;
    float* drow = xm + (size_t)r * DIM;
    #pragma unroll
    for (int t = 0; t < 3; ++t) {
        float4 v = *(const float4*)(srow + t * 256 + lane * 4);
        *(float4*)(drow + t * 256 + lane * 4) = v;
    }
}

extern "C" void kernel_launch(void* const* d_in, const int* in_sizes, int n_in,
                              void* d_out, int out_size, void* d_ws, size_t ws_size,
                              hipStream_t stream) {
    const float* x = (const float*)d_in[0];

    // d_out is float32, outputs concatenated flat: x_masked | mask | ids_restore
    float* out = (float*)d_out;
    float* out_xm      = out;                                   // 32*256*768
    float* out_mask    = out + (size_t)NBATCH * KEEP * DIM;     // 32*1024
    float* out_restore = out_mask + (size_t)NBATCH * LTOK;      // 32*1024

    // ws: term table (8 KiB) | packed counts (32768 x 16 B) | keep (32 KiB)
    double*     ws_term = (double*)d_ws;
    ulonglong2* ws_cnt  = (ulonglong2*)((char*)d_ws + 8192);
    int*        ws_keep = (int*)((char*)d_ws + 8192 + (size_t)NBATCH * LTOK * sizeof(ulonglong2));

    table_kernel<<<dim3(4), 256, 0, stream>>>(ws_term);
    ent_kernel<<<dim3(NBATCH * LTOK / 8), 256, 0, stream>>>(x, ws_cnt);
    rank_kernel<<<dim3(NBATCH, 8), 128, 0, stream>>>(ws_cnt, ws_term, ws_keep, out_mask, out_restore);
    gather_kernel<<<dim3(NBATCH * KEEP / 4), 256, 0, stream>>>(x, ws_keep, out_xm);
}